// Round 16
// baseline (50.787 us; speedup 1.0000x reference)
//
#include <hip/hip_runtime.h>

#define SELU_S  1.0507009873554805f
#define SELU_SA (1.0507009873554805f * 1.6732632423543772f)

typedef __attribute__((ext_vector_type(8)))  short        bf16x8;
typedef __attribute__((ext_vector_type(16))) float        f32x16;
typedef __attribute__((ext_vector_type(2)))  float        f32x2;
typedef __attribute__((ext_vector_type(4)))  unsigned int u32x4;

#define MFMA(a,b,c) __builtin_amdgcn_mfma_f32_32x32x16_bf16((a),(b),(c),0,0,0)
#define BC(u) __builtin_bit_cast(bf16x8, (u))

// One-time prepped weight fragments (written by prep_kernel, read by cnf_kernel).
// Layout (frag = 256 u32 = 64 lanes x 16 B):
//   0..3   L1 packed frags
//   4..27  W2 h(4..11) | m(12..19) | l(20..27)
//   28     quads: w1q[32] float4 | w4q[32] float4 (1 KB)
//   29..52 W3 h(29..36) | m(37..44) | l(45..52)   <- stays in GLOBAL
//   53*256 .. +127 : b2[64] | b3[64] as f32 bits  <- staged to LDS
// Session ledger (proven, R1-R15):
//   R5/R6: path-split + launch_bounds(256,3) => 3 blocks/CU. The occupancy win.
//   R7:    W3-in-LDS breaks 3-block residency => keep W3 global.
//   R3/R4: wave-stagger / MFMA-chain reorders: null.
//   R8/R10: runtime loops => scratch corruption/spill. LOOP-FREE body is law.
//   R12-R15: tangent precision shaves 230->134 MFMA, absmax frozen 0.09375
//          => argmax point is dx-path (z-path) only. 55.5 disp / 50.2 bench.
//   z-path PRECISION is closed: shaving 6->5 terms widens the SELU
//          branch-disagreement window 2^-24 -> 2^-16 => O(10^2-10^3) branch
//          flips x ~0.1 error each => near-certain fail. Do not touch terms.
//   R16 (this): z-chain ILP — split Ch into Cha+Chb (4 chains, ~32cyc
//          dependent spacing ~ MFMA latency), phase order flipped h-first so
//          Cu regs aren't live during phase-h (peak ~174). Reassociation only
//          (~1 ulp, branch-window magnitude unchanged).
__device__ __align__(16) unsigned int g_frags[53*256 + 128];

// ---- one-time (preprocessing) software RNE ----
__device__ __forceinline__ unsigned int rne_bits(float f){
    unsigned int b = __float_as_uint(f);
    return b + 0x7fffu + ((b >> 16) & 1u);
}
__device__ __forceinline__ unsigned short lvl16(float v, int lvl){
    unsigned int r0 = rne_bits(v);
    if (lvl == 0) return (unsigned short)(r0 >> 16);
    float v1 = v - __uint_as_float(r0 & 0xffff0000u);
    unsigned int r1 = rne_bits(v1);
    if (lvl == 1) return (unsigned short)(r1 >> 16);
    float v2 = v1 - __uint_as_float(r1 & 0xffff0000u);
    return (unsigned short)(rne_bits(v2) >> 16);
}

// ---- hot-path split primitive ----
__device__ __forceinline__ unsigned int cvtpk(float a, float b){
    unsigned int r;
    asm("v_cvt_pk_bf16_f32 %0, %1, %2" : "=v"(r) : "v"(a), "v"(b));
    return r;
}
__device__ __forceinline__ f32x2 unpk2(unsigned int p){
    f32x2 r;
    r.x = __uint_as_float(p << 16);
    r.y = __uint_as_float(p & 0xffff0000u);
    return r;
}
__device__ __forceinline__ f32x2 mk2(float v){ return f32x2{v, v}; }

__device__ __forceinline__ void split3_v(f32x2 v,
                                         unsigned int& hi, unsigned int& mi, unsigned int& lo){
    hi = cvtpk(v.x, v.y);
    f32x2 r1 = v - unpk2(hi);
    mi = cvtpk(r1.x, r1.y);
    f32x2 r2 = r1 - unpk2(mi);
    lo = cvtpk(r2.x, r2.y);                    // total residual <= 2^-24|v|
}
__device__ __forceinline__ void split3s(float a, float b,
                                        unsigned int& hi, unsigned int& mi, unsigned int& lo){
    split3_v(f32x2{a, b}, hi, mi, lo);
}

__device__ __forceinline__ f32x16 fzero(){
    f32x16 z;
    #pragma unroll
    for (int i = 0; i < 16; ++i) z[i] = 0.f;
    return z;
}

// works for both LDS-derived and global pointers (addrspace recovered after inlining)
__device__ __forceinline__ bf16x8 ldfrag(const unsigned int* src, int fid, int lane4){
    u32x4 u = *(const u32x4*)(src + fid*256 + lane4);
    return __builtin_bit_cast(bf16x8, u);
}

// SELU value+derivative for a packed pair
__device__ __forceinline__ void selu_pair(f32x2 z, f32x2& h, f32x2& d){
    f32x2 e{__expf(z.x), __expf(z.y)};
    f32x2 hn = e * mk2(SELU_SA) - mk2(SELU_SA);
    f32x2 hp = z * mk2(SELU_S);
    f32x2 dn = e * mk2(SELU_SA);
    h.x = z.x > 0.f ? hp.x : hn.x;
    h.y = z.y > 0.f ? hp.y : hn.y;
    d.x = z.x > 0.f ? SELU_S : dn.x;
    d.y = z.y > 0.f ? SELU_S : dn.y;
}

// C-layout (m74/m101): col = lane&31 = point, row = (r&3)+8*(r>>2)+4*(lane>>5), j = row+32t
// B in-lane bijection: per (kf,v,g):
//   j0 = 4g + (2v&3) + 8*(v>>1) + 16*(kf&1) + 32*(kf>>1), j1 = j0+1

// L1 epilogue (per t): z from Ch (b1 folded into MFMA); tangents = d * W1-cols.
// Tangent activations are single-level bf16 (cvtpk only, no lo split).
__device__ __forceinline__ void epilogue_L1(int t, const float4* __restrict__ w1q, int g,
                                            f32x16& Ch,
                                            u32x4 (&Bh)[3][4], u32x4 (&Bm0)[4], u32x4 (&Bl)[4]){
    #pragma unroll
    for (int kfh = 0; kfh < 2; ++kfh){
        const int kf = 2*t + kfh;
        #pragma unroll
        for (int v = 0; v < 4; ++v){
            const int r  = 8*kfh + 2*v;
            const int qi = (kf*4 + v)*2 + g;
            f32x2 z{Ch[r], Ch[r+1]};
            f32x2 h, d;
            selu_pair(z, h, d);
            float4 w = w1q[qi];             // {W1[j0,0],W1[j1,0],W1[j0,1],W1[j1,1]}
            f32x2 a = d * f32x2{w.x, w.y};
            f32x2 c = d * f32x2{w.z, w.w};
            unsigned int hi, mi, lo;
            split3_v(h, hi, mi, lo);
            Bh[0][kf][v] = hi; Bm0[kf][v] = mi; Bl[kf][v] = lo;
            Bh[1][kf][v] = cvtpk(a.x, a.y);
            Bh[2][kf][v] = cvtpk(c.x, c.y);
        }
    }
}

// Hidden layer, phase order h-FIRST -> merged tangent -> epilogue (R16):
//   phase-h : 48 MFMA into Cha/Chb — 4 independent chains (12-deep each);
//             Cha = ah*(Bh+Bm0+Bl) terms, Chb = am*Bh + am*Bm0 + al*Bh,
//             within-chain term order preserved; Ch = Cha + Chb (reassoc,
//             ~1 ulp — branch-window magnitude unchanged vs R15).
//             Cu not yet live => peak = fullB(80)+acc(64)+frags.
//   tangent : 16 MFMA — 1-term pure-bf16 (ah*Bu), independent 1-deep chains.
//   epilogue: unchanged.
// sched_barrier(0) fences stop cross-phase hoisting (R2 lesson).
// blds = LDS-resident bias table (2-address broadcast read, free).
template<bool FINAL>
__device__ __forceinline__ void hidden_layer(const unsigned int* wsrc, int lane4, int g,
                                             int fWh, int fWm, int fWl,
                                             const float* blds,
                                             const float4* __restrict__ w4q,
                                             u32x4 (&Bh)[3][4], u32x4 (&Bm0)[4], u32x4 (&Bl)[4],
                                             f32x2& dx0a, f32x2& dx1a, f32x2& tra){
    f32x16 Ch[2], Cu0[2], Cu1[2];

    // ---- phase-h: z-path, 6-term split across two accumulators (4 chains) ----
    {
        f32x16 Cha[2], Chb[2];
        Cha[0] = fzero(); Cha[1] = fzero();
        Chb[0] = fzero(); Chb[1] = fzero();
        __builtin_amdgcn_s_setprio(1);
        #pragma unroll
        for (int kf = 0; kf < 4; ++kf){
            #pragma unroll
            for (int t = 0; t < 2; ++t){
                const int q = t*4 + kf;
                bf16x8 ah = ldfrag(wsrc, fWh + q, lane4);
                bf16x8 am = ldfrag(wsrc, fWm + q, lane4);
                bf16x8 al = ldfrag(wsrc, fWl + q, lane4);
                // ah-terms (order: Bh, Bm0, Bl — as in the 6-term chain)
                Cha[t] = MFMA(ah, BC(Bl[kf]),
                         MFMA(ah, BC(Bm0[kf]),
                         MFMA(ah, BC(Bh[0][kf]), Cha[t])));
                // am/al-terms (order: am*Bh, am*Bm0, al*Bh)
                Chb[t] = MFMA(al, BC(Bh[0][kf]),
                         MFMA(am, BC(Bm0[kf]),
                         MFMA(am, BC(Bh[0][kf]), Chb[t])));
            }
        }
        __builtin_amdgcn_sched_barrier(0);
        Ch[0] = Cha[0] + Chb[0];
        Ch[1] = Cha[1] + Chb[1];
    }
    __builtin_amdgcn_sched_barrier(0);

    // ---- merged tangent phase: 1-term chains (pure bf16), shared ah frag ----
    Cu0[0] = fzero(); Cu0[1] = fzero();
    Cu1[0] = fzero(); Cu1[1] = fzero();
    #pragma unroll
    for (int kf = 0; kf < 4; ++kf){
        #pragma unroll
        for (int t = 0; t < 2; ++t){
            const int q = t*4 + kf;
            bf16x8 ah = ldfrag(wsrc, fWh + q, lane4);
            Cu0[t] = MFMA(ah, BC(Bh[1][kf]), Cu0[t]);
            Cu1[t] = MFMA(ah, BC(Bh[2][kf]), Cu1[t]);
        }
    }
    __builtin_amdgcn_s_setprio(0);
    __builtin_amdgcn_sched_barrier(0);

    // ---- epilogue (overwrites the SINGLE B buffer in place) ----
    #pragma unroll
    for (int kf = 0; kf < 4; ++kf){
        const int t = kf >> 1;
        #pragma unroll
        for (int v = 0; v < 4; ++v){
            const int r  = 8*(kf & 1) + 2*v;
            const int qi = (kf*4 + v)*2 + g;
            const int j0 = 4*g + ((2*v) & 3) + 8*(v >> 1) + 16*(kf & 1) + 32*(kf >> 1);
            float2 bb = *(const float2*)(blds + j0);    // LDS broadcast (2 addrs/wave)
            f32x2 z{Ch[t][r], Ch[t][r+1]};
            z = z + f32x2{bb.x, bb.y};
            f32x2 h, d;
            selu_pair(z, h, d);
            f32x2 a = d * f32x2{Cu0[t][r], Cu0[t][r+1]};
            f32x2 c = d * f32x2{Cu1[t][r], Cu1[t][r+1]};
            if (FINAL){
                float4 w = w4q[qi];         // {W4[0][j0],W4[0][j1],W4[1][j0],W4[1][j1]}
                f32x2 wxy{w.x, w.y}, wzw{w.z, w.w};
                dx0a = dx0a + wxy * h;
                dx1a = dx1a + wzw * h;
                tra  = tra  + wxy * a;
                tra  = tra  + wzw * c;
            } else {
                unsigned int hi, mi, lo;
                split3_v(h, hi, mi, lo);
                Bh[0][kf][v] = hi; Bm0[kf][v] = mi; Bl[kf][v] = lo;
                Bh[1][kf][v] = cvtpk(a.x, a.y);
                Bh[2][kf][v] = cvtpk(c.x, c.y);
            }
        }
    }
}

// ---------- one-time weight preprocessing (grid 22 x 64) ----------
__global__ void prep_kernel(const float* __restrict__ W1, const float* __restrict__ b1,
                            const float* __restrict__ W2, const float* __restrict__ W3,
                            const float* __restrict__ W4,
                            const float* __restrict__ b2, const float* __restrict__ b3)
{
    const int p  = blockIdx.x;
    const int ln = threadIdx.x;                 // 0..63
    const int g  = ln >> 5, l5 = ln & 31;
    if (p < 4){                                 // L1 packed frags
        const int t = p >> 1, var = p & 1;
        const int j = l5 + 32*t;
        const int lvl = (g == 0) ? 0 : (var == 0 ? 1 : 2);
        float vals[4] = { W1[j*3+0], W1[j*3+1], W1[j*3+2], b1[j] };
        unsigned int* ph = &g_frags[p*256 + ln*4];
        #pragma unroll
        for (int v = 0; v < 4; ++v){
            float a = (2*v   < 4) ? vals[2*v]   : 0.f;
            float b = (2*v+1 < 4) ? vals[2*v+1] : 0.f;
            unsigned int wa = (2*v   < 4) ? (unsigned int)lvl16(a, lvl) : 0u;
            unsigned int wb = (2*v+1 < 4) ? (unsigned int)lvl16(b, lvl) : 0u;
            ph[v] = wa | (wb << 16);
        }
    } else if (p < 20){                         // W2 / W3 triple-split frags
        const bool isW2 = (p < 12);
        const int q = p - (isW2 ? 4 : 12), t = q >> 2, kf = q & 3, m = l5 + 32*t;
        const float* __restrict__ Wg = isW2 ? W2 : W3;
        const int base = isW2 ? 4 : 29;
        unsigned int* ph = &g_frags[(base      + q)*256 + ln*4];
        unsigned int* pm = &g_frags[(base + 8  + q)*256 + ln*4];
        unsigned int* pl = &g_frags[(base + 16 + q)*256 + ln*4];
        #pragma unroll
        for (int v = 0; v < 4; ++v){
            int e0 = 2*v, e1 = 2*v + 1;
            int ja = 4*g + (e0&3) + 8*(e0>>2) + 16*(kf&1) + 32*(kf>>1);
            int jb = 4*g + (e1&3) + 8*(e1>>2) + 16*(kf&1) + 32*(kf>>1);
            float a = Wg[m*64 + ja], b = Wg[m*64 + jb];
            unsigned int ra = rne_bits(a), rb = rne_bits(b);
            ph[v] = (ra >> 16) | (rb & 0xffff0000u);
            float a1 = a - __uint_as_float(ra & 0xffff0000u);
            float b1v = b - __uint_as_float(rb & 0xffff0000u);
            unsigned int rma = rne_bits(a1), rmb = rne_bits(b1v);
            pm[v] = (rma >> 16) | (rmb & 0xffff0000u);
            float a2 = a1 - __uint_as_float(rma & 0xffff0000u);
            float b2v = b1v - __uint_as_float(rmb & 0xffff0000u);
            pl[v] = (rne_bits(a2) >> 16) | (rne_bits(b2v) & 0xffff0000u);
        }
    } else if (p == 20){                        // j-ordered fp32 quads
        if (ln < 32){
            const int qi = ln;                  // (kf*4+v)*2+g
            const int g2 = qi & 1, vv = (qi >> 1) & 3, kf = qi >> 3;
            const int j0 = 4*g2 + ((2*vv) & 3) + 8*(vv >> 1) + 16*(kf & 1) + 32*(kf >> 1);
            float4* w1q = (float4*)&g_frags[28*256];
            float4* w4q = w1q + 32;
            w1q[qi] = {W1[j0*3+0], W1[(j0+1)*3+0], W1[j0*3+1], W1[(j0+1)*3+1]};
            w4q[qi] = {W4[j0], W4[j0+1], W4[64+j0], W4[64+j0+1]};
        }
    } else {                                    // p == 21: bias tables (fp32 bits)
        g_frags[53*256      + ln] = __float_as_uint(b2[ln]);
        g_frags[53*256 + 64 + ln] = __float_as_uint(b3[ln]);
    }
}

// LDS image (29.5 KB): frags 0..27 (L1 + W2) + quads at frag 28 + b2|b3 (512 B)
#define OFF_Q (28*256)
#define OFF_B (29*256)
// launch_bounds(256,3): liveness budget 512/3 ~ 170; R16 phase-h peak ~174 is
// marginal — watch VGPR/occupancy/FETCH for spill (revert to R15 if so).
__global__ __launch_bounds__(256, 3) void cnf_kernel(
    const float* __restrict__ tp, const float* __restrict__ x,
    const float* __restrict__ b4, float* __restrict__ out)
{
    __shared__ unsigned int ldsA[29*256 + 128]; // 30208 B

    // ---------- stage prepped frags + biases: vectorized global->LDS copy ----------
    {
        const u32x4* __restrict__ src = (const u32x4*)g_frags;
        u32x4* dst = (u32x4*)ldsA;
        for (int i = threadIdx.x; i < 29*64; i += 256) dst[i] = src[i];
        if (threadIdx.x < 32){
            ((u32x4*)(ldsA + OFF_B))[threadIdx.x] =
                ((const u32x4*)(g_frags + 53*256))[threadIdx.x];
        }
    }
    __syncthreads();

    const float4* w1q = (const float4*)&ldsA[OFF_Q];
    const float4* w4q = w1q + 32;
    const float*  b2l = (const float*)(ldsA + OFF_B);
    const float*  b3l = b2l + 64;
    const unsigned int* gW3 = g_frags + 29*256; // W3 bank stays in global (L1/L2-hot)

    // ---------- main (one 32-point group per wave; loop-free body, see ledger) ----------
    const int lane  = threadIdx.x & 63;
    const int g     = lane >> 5, l5 = lane & 31;
    const int lane4 = lane * 4;
    const int wid   = blockIdx.x * 4 + (threadIdx.x >> 6);

    const float ts  = tp[0];

    unsigned int tsh, tsm, tsl;
    split3s(ts, 1.0f, tsh, tsm, tsl);        // [ts, 1.0]; 1.0 exact

    const int n = wid*32 + l5;
    const float x0 = x[n*3 + 0], x1 = x[n*3 + 1];

    unsigned int xh, xm, xl;
    split3s(x0, x1, xh, xm, xl);
    const u32x4 Bp1 = { g ? xm : xh, g ? tsm : tsh, 0u, 0u };   // -> AhBh + AmBm
    const u32x4 Bp2 = { g ? xh : xm, g ? tsh : tsm, 0u, 0u };   // -> AhBm + AmBh
    const u32x4 Bp3 = { g ? xh : xl, g ? tsh : tsl, 0u, 0u };   // -> AhBl + AlBh

    u32x4 Bh[3][4], Bm0[4], Bl[4];          // SINGLE layer-interface buffer (80 regs)
    f32x2 dx0a = mk2(0.f), dx1a = mk2(0.f), tra = mk2(0.f);

    // ----- layer 1: z = W1ext @ [x0,x1,t,1] (6-term via 3 packed MFMAs) -----
    #pragma unroll
    for (int t = 0; t < 2; ++t){
        bf16x8 F1 = ldfrag(ldsA, 2*t,     lane4);   // [W1h | W1m]
        bf16x8 F3 = ldfrag(ldsA, 2*t + 1, lane4);   // [W1h | W1l]
        __builtin_amdgcn_s_setprio(1);
        f32x16 Ch = MFMA(F3, BC(Bp3), MFMA(F1, BC(Bp2), MFMA(F1, BC(Bp1), fzero())));
        __builtin_amdgcn_s_setprio(0);
        epilogue_L1(t, w1q, g, Ch, Bh, Bm0, Bl);
    }

    // ----- layer 2 (LDS frags) / layer 3 (global frags, fp32 L4 fused) -----
    hidden_layer<false>(ldsA, lane4, g, 4, 12, 20, b2l, nullptr, Bh, Bm0, Bl, dx0a, dx1a, tra);
    hidden_layer<true >(gW3,  lane4, g, 0,  8, 16, b3l, w4q,     Bh, Bm0, Bl, dx0a, dx1a, tra);

    // ----- pair-reduce + cross-half reduce -----
    float dx0 = dx0a.x + dx0a.y;
    float dx1 = dx1a.x + dx1a.y;
    float tr  = tra.x  + tra.y;
    dx0 += __shfl_xor(dx0, 32, 64);
    dx1 += __shfl_xor(dx1, 32, 64);
    tr  += __shfl_xor(tr,  32, 64);
    if (g == 0){
        const float b40 = b4[0], b41 = b4[1];   // loaded late: keeps them out of
        out[n*3 + 0] = dx0 + b40;               // the whole-kernel live range
        out[n*3 + 1] = dx1 + b41;
        out[n*3 + 2] = tr;
    }
}

extern "C" void kernel_launch(void* const* d_in, const int* in_sizes, int n_in,
                              void* d_out, int out_size, void* d_ws, size_t ws_size,
                              hipStream_t stream) {
    const float* t  = (const float*)d_in[0];
    const float* x  = (const float*)d_in[1];
    const float* W1 = (const float*)d_in[2];
    const float* b1 = (const float*)d_in[3];
    const float* W2 = (const float*)d_in[4];
    const float* b2 = (const float*)d_in[5];
    const float* W3 = (const float*)d_in[6];
    const float* b3 = (const float*)d_in[7];
    const float* W4 = (const float*)d_in[8];
    const float* b4 = (const float*)d_in[9];
    float* out = (float*)d_out;

    prep_kernel<<<22, 64, 0, stream>>>(W1, b1, W2, W3, W4, b2, b3);
    cnf_kernel<<<2048, 256, 0, stream>>>(t, x, b4, out);
}

// Round 17
// 50.132 us; speedup vs baseline: 1.0131x; 1.0131x over previous
//
#include <hip/hip_runtime.h>

#define SELU_S  1.0507009873554805f
#define SELU_SA (1.0507009873554805f * 1.6732632423543772f)

typedef __attribute__((ext_vector_type(8)))  short        bf16x8;
typedef __attribute__((ext_vector_type(16))) float        f32x16;
typedef __attribute__((ext_vector_type(2)))  float        f32x2;
typedef __attribute__((ext_vector_type(4)))  unsigned int u32x4;

#define MFMA(a,b,c) __builtin_amdgcn_mfma_f32_32x32x16_bf16((a),(b),(c),0,0,0)
#define BC(u) __builtin_bit_cast(bf16x8, (u))

// One-time prepped weight fragments (written by prep_kernel, read by cnf_kernel).
// Layout (frag = 256 u32 = 64 lanes x 16 B):
//   0..3   L1 packed frags
//   4..27  W2 h(4..11) | m(12..19) | l(20..27)
//   28     quads: w1q[32] float4 | w4q[32] float4 (1 KB)
//   29..52 W3 h(29..36) | m(37..44) | l(45..52)   <- stays in GLOBAL
//   53*256 .. +127 : b2[64] | b3[64] as f32 bits  <- staged to LDS
// FINAL session ledger (R1-R16):
//   R5/R6: path-split + launch_bounds(256,3) => 3 blocks/CU. The occupancy win.
//   R7/R9: weight/bias data placement: insensitive.
//   R3/R4/R16: scheduling & ILP interventions: all null — latency already
//          hidden at 3 waves/SIMD.
//   R8/R10: runtime loops => scratch corruption/spill. LOOP-FREE body is law.
//   R12-R15: tangent precision ladder 230->134 MFMA (-42%), absmax frozen at
//          0.09375 throughout => argmax point lives on the dx/z-path only.
//   z-path precision closed: 6->5 terms widens the SELU branch-disagreement
//          window 2^-24 -> 2^-16 => O(10^2-3) branch flips => certain fail.
// This file is the VERIFIED BEST (R15): 55.5 us/dispatch, 50.17 us bench,
// absmax 0.09375 (threshold 0.113). Session: 70.8 -> 50.2 us (-29%).
__device__ __align__(16) unsigned int g_frags[53*256 + 128];

// ---- one-time (preprocessing) software RNE ----
__device__ __forceinline__ unsigned int rne_bits(float f){
    unsigned int b = __float_as_uint(f);
    return b + 0x7fffu + ((b >> 16) & 1u);
}
__device__ __forceinline__ unsigned short lvl16(float v, int lvl){
    unsigned int r0 = rne_bits(v);
    if (lvl == 0) return (unsigned short)(r0 >> 16);
    float v1 = v - __uint_as_float(r0 & 0xffff0000u);
    unsigned int r1 = rne_bits(v1);
    if (lvl == 1) return (unsigned short)(r1 >> 16);
    float v2 = v1 - __uint_as_float(r1 & 0xffff0000u);
    return (unsigned short)(rne_bits(v2) >> 16);
}

// ---- hot-path split primitive ----
__device__ __forceinline__ unsigned int cvtpk(float a, float b){
    unsigned int r;
    asm("v_cvt_pk_bf16_f32 %0, %1, %2" : "=v"(r) : "v"(a), "v"(b));
    return r;
}
__device__ __forceinline__ f32x2 unpk2(unsigned int p){
    f32x2 r;
    r.x = __uint_as_float(p << 16);
    r.y = __uint_as_float(p & 0xffff0000u);
    return r;
}
__device__ __forceinline__ f32x2 mk2(float v){ return f32x2{v, v}; }

__device__ __forceinline__ void split3_v(f32x2 v,
                                         unsigned int& hi, unsigned int& mi, unsigned int& lo){
    hi = cvtpk(v.x, v.y);
    f32x2 r1 = v - unpk2(hi);
    mi = cvtpk(r1.x, r1.y);
    f32x2 r2 = r1 - unpk2(mi);
    lo = cvtpk(r2.x, r2.y);                    // total residual <= 2^-24|v|
}
__device__ __forceinline__ void split3s(float a, float b,
                                        unsigned int& hi, unsigned int& mi, unsigned int& lo){
    split3_v(f32x2{a, b}, hi, mi, lo);
}

__device__ __forceinline__ f32x16 fzero(){
    f32x16 z;
    #pragma unroll
    for (int i = 0; i < 16; ++i) z[i] = 0.f;
    return z;
}

// works for both LDS-derived and global pointers (addrspace recovered after inlining)
__device__ __forceinline__ bf16x8 ldfrag(const unsigned int* src, int fid, int lane4){
    u32x4 u = *(const u32x4*)(src + fid*256 + lane4);
    return __builtin_bit_cast(bf16x8, u);
}

// SELU value+derivative for a packed pair
__device__ __forceinline__ void selu_pair(f32x2 z, f32x2& h, f32x2& d){
    f32x2 e{__expf(z.x), __expf(z.y)};
    f32x2 hn = e * mk2(SELU_SA) - mk2(SELU_SA);
    f32x2 hp = z * mk2(SELU_S);
    f32x2 dn = e * mk2(SELU_SA);
    h.x = z.x > 0.f ? hp.x : hn.x;
    h.y = z.y > 0.f ? hp.y : hn.y;
    d.x = z.x > 0.f ? SELU_S : dn.x;
    d.y = z.y > 0.f ? SELU_S : dn.y;
}

// C-layout (m74/m101): col = lane&31 = point, row = (r&3)+8*(r>>2)+4*(lane>>5), j = row+32t
// B in-lane bijection: per (kf,v,g):
//   j0 = 4g + (2v&3) + 8*(v>>1) + 16*(kf&1) + 32*(kf>>1), j1 = j0+1

// L1 epilogue (per t): z from Ch (b1 folded into MFMA); tangents = d * W1-cols.
// Tangent activations are single-level bf16 (cvtpk only, no lo split).
__device__ __forceinline__ void epilogue_L1(int t, const float4* __restrict__ w1q, int g,
                                            f32x16& Ch,
                                            u32x4 (&Bh)[3][4], u32x4 (&Bm0)[4], u32x4 (&Bl)[4]){
    #pragma unroll
    for (int kfh = 0; kfh < 2; ++kfh){
        const int kf = 2*t + kfh;
        #pragma unroll
        for (int v = 0; v < 4; ++v){
            const int r  = 8*kfh + 2*v;
            const int qi = (kf*4 + v)*2 + g;
            f32x2 z{Ch[r], Ch[r+1]};
            f32x2 h, d;
            selu_pair(z, h, d);
            float4 w = w1q[qi];             // {W1[j0,0],W1[j1,0],W1[j0,1],W1[j1,1]}
            f32x2 a = d * f32x2{w.x, w.y};
            f32x2 c = d * f32x2{w.z, w.w};
            unsigned int hi, mi, lo;
            split3_v(h, hi, mi, lo);
            Bh[0][kf][v] = hi; Bm0[kf][v] = mi; Bl[kf][v] = lo;
            Bh[1][kf][v] = cvtpk(a.x, a.y);
            Bh[2][kf][v] = cvtpk(c.x, c.y);
        }
    }
}

// Hidden layer, PATH-SPLIT form, phase order (merged tangent) -> h:
//   tangent phase: 16 MFMA — ONE term per path (pure bf16: ah*Bu), 4
//                  independent 1-deep chains per iter, ah loaded once (R15).
//   phase-h     : 48 MFMA into Ch — full 6-term z-path (residual ~2^-24).
// Liveness: tangent = B(80)+Cu(64)+frag ~152 <= 170 budget; phase-h
// unchanged. sched_barrier(0) fences stop cross-phase hoisting (R2 lesson).
// blds = LDS-resident bias table (2-address broadcast read, free).
template<bool FINAL>
__device__ __forceinline__ void hidden_layer(const unsigned int* wsrc, int lane4, int g,
                                             int fWh, int fWm, int fWl,
                                             const float* blds,
                                             const float4* __restrict__ w4q,
                                             u32x4 (&Bh)[3][4], u32x4 (&Bm0)[4], u32x4 (&Bl)[4],
                                             f32x2& dx0a, f32x2& dx1a, f32x2& tra){
    f32x16 Ch[2], Cu0[2], Cu1[2];

    // ---- merged tangent phase: 1-term chains (pure bf16), shared ah frag ----
    Cu0[0] = fzero(); Cu0[1] = fzero();
    Cu1[0] = fzero(); Cu1[1] = fzero();
    __builtin_amdgcn_s_setprio(1);
    #pragma unroll
    for (int kf = 0; kf < 4; ++kf){
        #pragma unroll
        for (int t = 0; t < 2; ++t){
            const int q = t*4 + kf;
            bf16x8 ah = ldfrag(wsrc, fWh + q, lane4);
            Cu0[t] = MFMA(ah, BC(Bh[1][kf]), Cu0[t]);
            Cu1[t] = MFMA(ah, BC(Bh[2][kf]), Cu1[t]);
        }
    }
    __builtin_amdgcn_sched_barrier(0);

    // ---- phase-h: z-path, 6-term (residual ~2^-24, unchanged) ----
    Ch[0] = fzero(); Ch[1] = fzero();
    #pragma unroll
    for (int kf = 0; kf < 4; ++kf){
        #pragma unroll
        for (int t = 0; t < 2; ++t){
            const int q = t*4 + kf;
            bf16x8 ah = ldfrag(wsrc, fWh + q, lane4);
            bf16x8 am = ldfrag(wsrc, fWm + q, lane4);
            bf16x8 al = ldfrag(wsrc, fWl + q, lane4);
            Ch[t] = MFMA(al, BC(Bh[0][kf]),
                    MFMA(am, BC(Bm0[kf]),
                    MFMA(ah, BC(Bl[kf]),
                    MFMA(am, BC(Bh[0][kf]),
                    MFMA(ah, BC(Bm0[kf]),
                    MFMA(ah, BC(Bh[0][kf]), Ch[t]))))));
        }
    }
    __builtin_amdgcn_s_setprio(0);
    __builtin_amdgcn_sched_barrier(0);

    // ---- epilogue (overwrites the SINGLE B buffer in place) ----
    #pragma unroll
    for (int kf = 0; kf < 4; ++kf){
        const int t = kf >> 1;
        #pragma unroll
        for (int v = 0; v < 4; ++v){
            const int r  = 8*(kf & 1) + 2*v;
            const int qi = (kf*4 + v)*2 + g;
            const int j0 = 4*g + ((2*v) & 3) + 8*(v >> 1) + 16*(kf & 1) + 32*(kf >> 1);
            float2 bb = *(const float2*)(blds + j0);    // LDS broadcast (2 addrs/wave)
            f32x2 z{Ch[t][r], Ch[t][r+1]};
            z = z + f32x2{bb.x, bb.y};
            f32x2 h, d;
            selu_pair(z, h, d);
            f32x2 a = d * f32x2{Cu0[t][r], Cu0[t][r+1]};
            f32x2 c = d * f32x2{Cu1[t][r], Cu1[t][r+1]};
            if (FINAL){
                float4 w = w4q[qi];         // {W4[0][j0],W4[0][j1],W4[1][j0],W4[1][j1]}
                f32x2 wxy{w.x, w.y}, wzw{w.z, w.w};
                dx0a = dx0a + wxy * h;
                dx1a = dx1a + wzw * h;
                tra  = tra  + wxy * a;
                tra  = tra  + wzw * c;
            } else {
                unsigned int hi, mi, lo;
                split3_v(h, hi, mi, lo);
                Bh[0][kf][v] = hi; Bm0[kf][v] = mi; Bl[kf][v] = lo;
                Bh[1][kf][v] = cvtpk(a.x, a.y);
                Bh[2][kf][v] = cvtpk(c.x, c.y);
            }
        }
    }
}

// ---------- one-time weight preprocessing (grid 22 x 64) ----------
__global__ void prep_kernel(const float* __restrict__ W1, const float* __restrict__ b1,
                            const float* __restrict__ W2, const float* __restrict__ W3,
                            const float* __restrict__ W4,
                            const float* __restrict__ b2, const float* __restrict__ b3)
{
    const int p  = blockIdx.x;
    const int ln = threadIdx.x;                 // 0..63
    const int g  = ln >> 5, l5 = ln & 31;
    if (p < 4){                                 // L1 packed frags
        const int t = p >> 1, var = p & 1;
        const int j = l5 + 32*t;
        const int lvl = (g == 0) ? 0 : (var == 0 ? 1 : 2);
        float vals[4] = { W1[j*3+0], W1[j*3+1], W1[j*3+2], b1[j] };
        unsigned int* ph = &g_frags[p*256 + ln*4];
        #pragma unroll
        for (int v = 0; v < 4; ++v){
            float a = (2*v   < 4) ? vals[2*v]   : 0.f;
            float b = (2*v+1 < 4) ? vals[2*v+1] : 0.f;
            unsigned int wa = (2*v   < 4) ? (unsigned int)lvl16(a, lvl) : 0u;
            unsigned int wb = (2*v+1 < 4) ? (unsigned int)lvl16(b, lvl) : 0u;
            ph[v] = wa | (wb << 16);
        }
    } else if (p < 20){                         // W2 / W3 triple-split frags
        const bool isW2 = (p < 12);
        const int q = p - (isW2 ? 4 : 12), t = q >> 2, kf = q & 3, m = l5 + 32*t;
        const float* __restrict__ Wg = isW2 ? W2 : W3;
        const int base = isW2 ? 4 : 29;
        unsigned int* ph = &g_frags[(base      + q)*256 + ln*4];
        unsigned int* pm = &g_frags[(base + 8  + q)*256 + ln*4];
        unsigned int* pl = &g_frags[(base + 16 + q)*256 + ln*4];
        #pragma unroll
        for (int v = 0; v < 4; ++v){
            int e0 = 2*v, e1 = 2*v + 1;
            int ja = 4*g + (e0&3) + 8*(e0>>2) + 16*(kf&1) + 32*(kf>>1);
            int jb = 4*g + (e1&3) + 8*(e1>>2) + 16*(kf&1) + 32*(kf>>1);
            float a = Wg[m*64 + ja], b = Wg[m*64 + jb];
            unsigned int ra = rne_bits(a), rb = rne_bits(b);
            ph[v] = (ra >> 16) | (rb & 0xffff0000u);
            float a1 = a - __uint_as_float(ra & 0xffff0000u);
            float b1v = b - __uint_as_float(rb & 0xffff0000u);
            unsigned int rma = rne_bits(a1), rmb = rne_bits(b1v);
            pm[v] = (rma >> 16) | (rmb & 0xffff0000u);
            float a2 = a1 - __uint_as_float(rma & 0xffff0000u);
            float b2v = b1v - __uint_as_float(rmb & 0xffff0000u);
            pl[v] = (rne_bits(a2) >> 16) | (rne_bits(b2v) & 0xffff0000u);
        }
    } else if (p == 20){                        // j-ordered fp32 quads
        if (ln < 32){
            const int qi = ln;                  // (kf*4+v)*2+g
            const int g2 = qi & 1, vv = (qi >> 1) & 3, kf = qi >> 3;
            const int j0 = 4*g2 + ((2*vv) & 3) + 8*(vv >> 1) + 16*(kf & 1) + 32*(kf >> 1);
            float4* w1q = (float4*)&g_frags[28*256];
            float4* w4q = w1q + 32;
            w1q[qi] = {W1[j0*3+0], W1[(j0+1)*3+0], W1[j0*3+1], W1[(j0+1)*3+1]};
            w4q[qi] = {W4[j0], W4[j0+1], W4[64+j0], W4[64+j0+1]};
        }
    } else {                                    // p == 21: bias tables (fp32 bits)
        g_frags[53*256      + ln] = __float_as_uint(b2[ln]);
        g_frags[53*256 + 64 + ln] = __float_as_uint(b3[ln]);
    }
}

// LDS image (29.5 KB): frags 0..27 (L1 + W2) + quads at frag 28 + b2|b3 (512 B)
#define OFF_Q (28*256)
#define OFF_B (29*256)
// launch_bounds(256,3): path-split keeps peak liveness within the 512/3=170
// budget (R6/R9/R11-R15: 3 blocks/CU, no spill).
__global__ __launch_bounds__(256, 3) void cnf_kernel(
    const float* __restrict__ tp, const float* __restrict__ x,
    const float* __restrict__ b4, float* __restrict__ out)
{
    __shared__ unsigned int ldsA[29*256 + 128]; // 30208 B

    // ---------- stage prepped frags + biases: vectorized global->LDS copy ----------
    {
        const u32x4* __restrict__ src = (const u32x4*)g_frags;
        u32x4* dst = (u32x4*)ldsA;
        for (int i = threadIdx.x; i < 29*64; i += 256) dst[i] = src[i];
        if (threadIdx.x < 32){
            ((u32x4*)(ldsA + OFF_B))[threadIdx.x] =
                ((const u32x4*)(g_frags + 53*256))[threadIdx.x];
        }
    }
    __syncthreads();

    const float4* w1q = (const float4*)&ldsA[OFF_Q];
    const float4* w4q = w1q + 32;
    const float*  b2l = (const float*)(ldsA + OFF_B);
    const float*  b3l = b2l + 64;
    const unsigned int* gW3 = g_frags + 29*256; // W3 bank stays in global (L1/L2-hot)

    // ---------- main (one 32-point group per wave; loop-free body, see ledger) ----------
    const int lane  = threadIdx.x & 63;
    const int g     = lane >> 5, l5 = lane & 31;
    const int lane4 = lane * 4;
    const int wid   = blockIdx.x * 4 + (threadIdx.x >> 6);

    const float ts  = tp[0];

    unsigned int tsh, tsm, tsl;
    split3s(ts, 1.0f, tsh, tsm, tsl);        // [ts, 1.0]; 1.0 exact

    const int n = wid*32 + l5;
    const float x0 = x[n*3 + 0], x1 = x[n*3 + 1];

    unsigned int xh, xm, xl;
    split3s(x0, x1, xh, xm, xl);
    const u32x4 Bp1 = { g ? xm : xh, g ? tsm : tsh, 0u, 0u };   // -> AhBh + AmBm
    const u32x4 Bp2 = { g ? xh : xm, g ? tsh : tsm, 0u, 0u };   // -> AhBm + AmBh
    const u32x4 Bp3 = { g ? xh : xl, g ? tsh : tsl, 0u, 0u };   // -> AhBl + AlBh

    u32x4 Bh[3][4], Bm0[4], Bl[4];          // SINGLE layer-interface buffer (80 regs)
    f32x2 dx0a = mk2(0.f), dx1a = mk2(0.f), tra = mk2(0.f);

    // ----- layer 1: z = W1ext @ [x0,x1,t,1] (6-term via 3 packed MFMAs) -----
    #pragma unroll
    for (int t = 0; t < 2; ++t){
        bf16x8 F1 = ldfrag(ldsA, 2*t,     lane4);   // [W1h | W1m]
        bf16x8 F3 = ldfrag(ldsA, 2*t + 1, lane4);   // [W1h | W1l]
        __builtin_amdgcn_s_setprio(1);
        f32x16 Ch = MFMA(F3, BC(Bp3), MFMA(F1, BC(Bp2), MFMA(F1, BC(Bp1), fzero())));
        __builtin_amdgcn_s_setprio(0);
        epilogue_L1(t, w1q, g, Ch, Bh, Bm0, Bl);
    }

    // ----- layer 2 (LDS frags) / layer 3 (global frags, fp32 L4 fused) -----
    hidden_layer<false>(ldsA, lane4, g, 4, 12, 20, b2l, nullptr, Bh, Bm0, Bl, dx0a, dx1a, tra);
    hidden_layer<true >(gW3,  lane4, g, 0,  8, 16, b3l, w4q,     Bh, Bm0, Bl, dx0a, dx1a, tra);

    // ----- pair-reduce + cross-half reduce -----
    float dx0 = dx0a.x + dx0a.y;
    float dx1 = dx1a.x + dx1a.y;
    float tr  = tra.x  + tra.y;
    dx0 += __shfl_xor(dx0, 32, 64);
    dx1 += __shfl_xor(dx1, 32, 64);
    tr  += __shfl_xor(tr,  32, 64);
    if (g == 0){
        const float b40 = b4[0], b41 = b4[1];   // loaded late: keeps them out of
        out[n*3 + 0] = dx0 + b40;               // the whole-kernel live range
        out[n*3 + 1] = dx1 + b41;
        out[n*3 + 2] = tr;
    }
}

extern "C" void kernel_launch(void* const* d_in, const int* in_sizes, int n_in,
                              void* d_out, int out_size, void* d_ws, size_t ws_size,
                              hipStream_t stream) {
    const float* t  = (const float*)d_in[0];
    const float* x  = (const float*)d_in[1];
    const float* W1 = (const float*)d_in[2];
    const float* b1 = (const float*)d_in[3];
    const float* W2 = (const float*)d_in[4];
    const float* b2 = (const float*)d_in[5];
    const float* W3 = (const float*)d_in[6];
    const float* b3 = (const float*)d_in[7];
    const float* W4 = (const float*)d_in[8];
    const float* b4 = (const float*)d_in[9];
    float* out = (float*)d_out;

    prep_kernel<<<22, 64, 0, stream>>>(W1, b1, W2, W3, W4, b2, b3);
    cnf_kernel<<<2048, 256, 0, stream>>>(t, x, b4, out);
}